// Round 2
// baseline (853.144 us; speedup 1.0000x reference)
//
#include <hip/hip_runtime.h>
#include <hip/hip_bf16.h>

// ---------------------------------------------------------------------------
// Swin WindowAttention fused kernel, v2: in-register layout transforms.
//   - LDS only 32 KiB (x tile, reused as attn-out for proj) -> 2 blocks/CU
//   - q,k transposed via identity-MFMA (16x16x16); V/P fragments are
//     lane-local by construction (swapped-operand scores, K=16 PV).
//   - combined (rel_bias + window mask + key-pad -inf) precomputed in the
//     exact per-lane layout -> coalesced loads, no masking in hot loop.
// ---------------------------------------------------------------------------

#define NTOK 49
static constexpr float SCALE_Q = 0.17677669529663687f; // 32^-0.5

using bf16   = __bf16;
using bf16x4 = __attribute__((ext_vector_type(4))) __bf16;
using bf16x8 = __attribute__((ext_vector_type(8))) __bf16;
using short4v = __attribute__((ext_vector_type(4))) short;
using f32x4  = __attribute__((ext_vector_type(4))) float;

#define WT_QKV_OFF 0
#define WT_PROJ_OFF (768 * 256 * 2)
#define CB_OFF (WT_PROJ_OFF + 256 * 256 * 2)
#define WS_NEEDED (CB_OFF + (size_t)64 * 8 * 4096 * 4)

// ---- 16x16x16 bf16 MFMA wrapper (builtin-name portability) ----
static __device__ __forceinline__ f32x4 mfma16(bf16x4 a, bf16x4 b, f32x4 c) {
#if __has_builtin(__builtin_amdgcn_mfma_f32_16x16x16_bf16)
    return __builtin_amdgcn_mfma_f32_16x16x16_bf16(a, b, c, 0, 0, 0);
#elif __has_builtin(__builtin_amdgcn_mfma_f32_16x16x16bf16_1k)
    return __builtin_amdgcn_mfma_f32_16x16x16bf16_1k(
        __builtin_bit_cast(short4v, a), __builtin_bit_cast(short4v, b), c, 0, 0, 0);
#elif __has_builtin(__builtin_amdgcn_mfma_f32_16x16x16_bf16_1k)
    return __builtin_amdgcn_mfma_f32_16x16x16_bf16_1k(
        __builtin_bit_cast(short4v, a), __builtin_bit_cast(short4v, b), c, 0, 0, 0);
#else
    asm volatile("v_mfma_f32_16x16x16_bf16 %0, %1, %2, %0\n\t"
                 "s_nop 7\n\ts_nop 7\n\ts_nop 1"
                 : "+v"(c) : "v"(a), "v"(b));
    return c;
#endif
}

// ---- precompute kernels ----
__global__ void prep_wqkv(const float* __restrict__ qkv_w, bf16* __restrict__ wt) {
    int idx = blockIdx.x * 256 + threadIdx.x;            // 768*256
    if (idx >= 768 * 256) return;
    int n = idx >> 8, k = idx & 255;
    float v = qkv_w[k * 768 + n];
    if (n < 256) v *= SCALE_Q;                           // fold q-scale
    wt[idx] = (bf16)v;                                   // wt[n][k]
}
__global__ void prep_wproj(const float* __restrict__ proj_w, bf16* __restrict__ wt) {
    int idx = blockIdx.x * 256 + threadIdx.x;            // 256*256
    if (idx >= 256 * 256) return;
    int n = idx >> 8, k = idx & 255;
    wt[idx] = (bf16)proj_w[k * 256 + n];                 // wt[n][k]
}
// cb2[w][h][kt][qt][r][lane]: score addend for q=16qt+(lane&15),
// key=16kt+4*(lane>>4)+r.  -1e30 for key>=49 (pad), 0 for q>=49 (dead rows).
__global__ void prep_cb2(const float* __restrict__ bias_table, const int* __restrict__ rel_index,
                         const float* __restrict__ mask, float* __restrict__ cb2) {
    int idx = blockIdx.x * 256 + threadIdx.x;            // 64*8*4*4*4*64
    if (idx >= 64 * 8 * 4096) return;
    int lane = idx & 63;
    int t = idx >> 6;
    int r  = t & 3; t >>= 2;
    int qt = t & 3; t >>= 2;
    int kt = t & 3; t >>= 2;
    int h  = t & 7;
    int w  = t >> 3;
    int i = qt * 16 + (lane & 15);
    int j = kt * 16 + (lane >> 4) * 4 + r;
    float v;
    if (j >= NTOK)      v = -1e30f;
    else if (i >= NTOK) v = 0.0f;
    else v = bias_table[rel_index[i * 49 + j] * 8 + h] + mask[(w * 49 + i) * 49 + j];
    cb2[idx] = v;
}

__global__ __launch_bounds__(512, 4) void fused_attn(
    const float* __restrict__ x,
    const float* __restrict__ qkv_b,
    const float* __restrict__ proj_b,
    const bf16* __restrict__ wt_qkv,
    const bf16* __restrict__ wt_proj,
    const float* __restrict__ cb2,
    float* __restrict__ out)
{
    __shared__ char xs[32768];       // x tile (bf16, swizzled); later attn-out
    const int b    = blockIdx.x;
    const int tid  = threadIdx.x;
    const int lane = tid & 63;
    const int h    = tid >> 6;       // wave id == head
    const int c    = lane & 15;
    const int g    = lane >> 4;

    // ---- stage x -> xs (bf16, rows 49..63 zeroed, swizzled) ----
    {
        const float* xb = x + (size_t)b * (NTOK * 256);
        #pragma unroll
        for (int it = 0; it < 8; ++it) {
            int idx = it * 512 + tid;          // 64 rows x 64 float4-chunks
            int row = idx >> 6, c4 = idx & 63;
            float4 v = make_float4(0.f, 0.f, 0.f, 0.f);
            if (row < NTOK) v = ((const float4*)xb)[row * 64 + c4];
            bf16x4 o;
            o[0] = (bf16)v.x; o[1] = (bf16)v.y; o[2] = (bf16)v.z; o[3] = (bf16)v.w;
            *(bf16x4*)(xs + row * 512 + ((c4 * 8) ^ ((row & 7) << 4))) = o;
        }
    }
    __syncthreads();

    // identity B-fragment for the transpose-MFMA: B[k][col] = (k==col)
    bf16x4 iden;
    #pragma unroll
    for (int j = 0; j < 4; ++j) iden[j] = (bf16)((4 * g + j == c) ? 1.0f : 0.0f);

    // ---- QKV pass 1: q,k  ([64x256] @ [256x64] per wave) ----
    bf16x4 qf[4][2];   // [qt][ct]  B-frag for scores
    bf16x4 kf[4][2];   // [kt][ct]  A-frag for scores
    {
        f32x4 acc[4][4];   // [ni][mi]: ni 0,1=q chans 0-15,16-31; 2,3=k
        #pragma unroll
        for (int ni = 0; ni < 4; ++ni)
            #pragma unroll
            for (int mi = 0; mi < 4; ++mi)
                acc[ni][mi] = (f32x4){0.f, 0.f, 0.f, 0.f};

        #pragma unroll
        for (int kk = 0; kk < 8; ++kk) {
            bf16x8 a[4];
            #pragma unroll
            for (int mi = 0; mi < 4; ++mi) {
                int row = mi * 16 + c;
                a[mi] = *(const bf16x8*)(xs + row * 512 + ((kk * 64 + g * 16) ^ ((row & 7) << 4)));
            }
            #pragma unroll
            for (int ni = 0; ni < 4; ++ni) {
                int ncol = (ni < 2 ? h * 32 + ni * 16 : 256 + h * 32 + (ni - 2) * 16) + c;
                bf16x8 bfr = *(const bf16x8*)(wt_qkv + ncol * 256 + kk * 32 + g * 8);
                #pragma unroll
                for (int mi = 0; mi < 4; ++mi)
                    acc[ni][mi] = __builtin_amdgcn_mfma_f32_16x16x32_bf16(a[mi], bfr, acc[ni][mi], 0, 0, 0);
            }
        }
        // +bias, pack bf16, transpose via identity-MFMA (stays in registers)
        #pragma unroll
        for (int ni = 0; ni < 4; ++ni) {
            int col = (ni < 2 ? h * 32 + ni * 16 : 256 + h * 32 + (ni - 2) * 16) + c;
            float bias = qkv_b[col];
            if (ni < 2) bias *= SCALE_Q;
            #pragma unroll
            for (int mi = 0; mi < 4; ++mi) {
                bf16x4 in;
                #pragma unroll
                for (int r = 0; r < 4; ++r) in[r] = (bf16)(acc[ni][mi][r] + bias);
                f32x4 t = mfma16(in, iden, (f32x4){0.f, 0.f, 0.f, 0.f});
                bf16x4 o;
                #pragma unroll
                for (int r = 0; r < 4; ++r) o[r] = (bf16)t[r];
                if (ni < 2) qf[mi][ni] = o;
                else        kf[mi][ni - 2] = o;
            }
        }
    }

    // ---- QKV pass 2: v  (C-frag == PV A-frag, no transform) ----
    bf16x4 vf[2][4];   // [dt][kt]
    {
        f32x4 accv[2][4];
        #pragma unroll
        for (int dt = 0; dt < 2; ++dt)
            #pragma unroll
            for (int mi = 0; mi < 4; ++mi)
                accv[dt][mi] = (f32x4){0.f, 0.f, 0.f, 0.f};

        #pragma unroll
        for (int kk = 0; kk < 8; ++kk) {
            bf16x8 a[4];
            #pragma unroll
            for (int mi = 0; mi < 4; ++mi) {
                int row = mi * 16 + c;
                a[mi] = *(const bf16x8*)(xs + row * 512 + ((kk * 64 + g * 16) ^ ((row & 7) << 4)));
            }
            #pragma unroll
            for (int dt = 0; dt < 2; ++dt) {
                int ncol = 512 + h * 32 + dt * 16 + c;
                bf16x8 bfr = *(const bf16x8*)(wt_qkv + ncol * 256 + kk * 32 + g * 8);
                #pragma unroll
                for (int mi = 0; mi < 4; ++mi)
                    accv[dt][mi] = __builtin_amdgcn_mfma_f32_16x16x32_bf16(a[mi], bfr, accv[dt][mi], 0, 0, 0);
            }
        }
        #pragma unroll
        for (int dt = 0; dt < 2; ++dt) {
            float vb = qkv_b[512 + h * 32 + dt * 16 + c];
            #pragma unroll
            for (int kt = 0; kt < 4; ++kt) {
                #pragma unroll
                for (int r = 0; r < 4; ++r) vf[dt][kt][r] = (bf16)(accv[dt][kt][r] + vb);
            }
        }
    }
    __syncthreads();   // last xs read done; xs becomes attn-out buffer

    // ---- attention: per q-tile scores -> softmax -> PV (all in registers) --
    f32x4 oT[2][4];    // [dt][qt]
    #pragma unroll
    for (int dt = 0; dt < 2; ++dt)
        #pragma unroll
        for (int qt = 0; qt < 4; ++qt)
            oT[dt][qt] = (f32x4){0.f, 0.f, 0.f, 0.f};

    const float* cbw = cb2 + ((size_t)((b & 63) * 8 + h)) * 4096;
    #pragma unroll
    for (int qt = 0; qt < 4; ++qt) {
        f32x4 sT[4];
        #pragma unroll
        for (int kt = 0; kt < 4; ++kt) {
            sT[kt] = (f32x4){0.f, 0.f, 0.f, 0.f};
            sT[kt] = mfma16(kf[kt][0], qf[qt][0], sT[kt]);
            sT[kt] = mfma16(kf[kt][1], qf[qt][1], sT[kt]);
        }
        // + (rel_bias + mask + keypad) in exact lane layout, coalesced
        #pragma unroll
        for (int kt = 0; kt < 4; ++kt)
            #pragma unroll
            for (int r = 0; r < 4; ++r)
                sT[kt][r] += cbw[((kt * 4 + qt) * 4 + r) * 64 + lane];
        // softmax over 64 keys: 16 in-lane + reduce across the 4 g-lanes
        float m = sT[0][0];
        #pragma unroll
        for (int kt = 0; kt < 4; ++kt)
            #pragma unroll
            for (int r = 0; r < 4; ++r) m = fmaxf(m, sT[kt][r]);
        m = fmaxf(m, __shfl_xor(m, 16));
        m = fmaxf(m, __shfl_xor(m, 32));
        float sum = 0.f;
        #pragma unroll
        for (int kt = 0; kt < 4; ++kt)
            #pragma unroll
            for (int r = 0; r < 4; ++r) {
                float e = __expf(sT[kt][r] - m);
                sT[kt][r] = e;
                sum += e;
            }
        sum += __shfl_xor(sum, 16);
        sum += __shfl_xor(sum, 32);
        float rs = 1.f / sum;
        bf16x4 pB[4];
        #pragma unroll
        for (int kt = 0; kt < 4; ++kt)
            #pragma unroll
            for (int r = 0; r < 4; ++r) pB[kt][r] = (bf16)(sT[kt][r] * rs);
        // PV: out^T tile accumulate (P frag is softmax output verbatim)
        #pragma unroll
        for (int kt = 0; kt < 4; ++kt)
            #pragma unroll
            for (int dt = 0; dt < 2; ++dt)
                oT[dt][qt] = mfma16(vf[dt][kt], pB[kt], oT[dt][qt]);
    }

    // ---- attn-out -> xs (bf16x4 vectorized, swizzled) ----
    #pragma unroll
    for (int qt = 0; qt < 4; ++qt) {
        int row = qt * 16 + c;
        #pragma unroll
        for (int dt = 0; dt < 2; ++dt) {
            int cbyte = h * 64 + dt * 32 + g * 8;
            bf16x4 o;
            #pragma unroll
            for (int r = 0; r < 4; ++r) o[r] = (bf16)oT[dt][qt][r];
            *(bf16x4*)(xs + row * 512 + (cbyte ^ ((row & 7) << 4))) = o;
        }
    }
    __syncthreads();

    // ---- proj: [64x256] @ [256x32] per wave + bias -> out ----
    {
        f32x4 po[2][4];
        #pragma unroll
        for (int ni = 0; ni < 2; ++ni)
            #pragma unroll
            for (int mi = 0; mi < 4; ++mi)
                po[ni][mi] = (f32x4){0.f, 0.f, 0.f, 0.f};

        #pragma unroll
        for (int kk = 0; kk < 8; ++kk) {
            bf16x8 a[4];
            #pragma unroll
            for (int mi = 0; mi < 4; ++mi) {
                int row = mi * 16 + c;
                a[mi] = *(const bf16x8*)(xs + row * 512 + ((kk * 64 + g * 16) ^ ((row & 7) << 4)));
            }
            #pragma unroll
            for (int ni = 0; ni < 2; ++ni) {
                int col = h * 32 + ni * 16 + c;
                bf16x8 bw = *(const bf16x8*)(wt_proj + col * 256 + kk * 32 + g * 8);
                #pragma unroll
                for (int mi = 0; mi < 4; ++mi)
                    po[ni][mi] = __builtin_amdgcn_mfma_f32_16x16x32_bf16(a[mi], bw, po[ni][mi], 0, 0, 0);
            }
        }
        float* outb = out + (size_t)b * (NTOK * 256);
        #pragma unroll
        for (int ni = 0; ni < 2; ++ni) {
            int col = h * 32 + ni * 16 + c;
            float pb = proj_b[col];
            #pragma unroll
            for (int mi = 0; mi < 4; ++mi) {
                #pragma unroll
                for (int r = 0; r < 4; ++r) {
                    int row = mi * 16 + g * 4 + r;
                    if (row < NTOK) outb[row * 256 + col] = po[ni][mi][r] + pb;
                }
            }
        }
    }
}

extern "C" void kernel_launch(void* const* d_in, const int* in_sizes, int n_in,
                              void* d_out, int out_size, void* d_ws, size_t ws_size,
                              hipStream_t stream) {
    const float* x          = (const float*)d_in[0];
    const float* mask       = (const float*)d_in[1];
    const float* qkv_w      = (const float*)d_in[2];
    const float* qkv_b      = (const float*)d_in[3];
    const float* proj_w     = (const float*)d_in[4];
    const float* proj_b     = (const float*)d_in[5];
    const float* bias_table = (const float*)d_in[6];
    const int*   rel_index  = (const int*)d_in[7];
    float* out = (float*)d_out;

    if (ws_size < WS_NEEDED) return;  // needs ~8.9 MB scratch

    char* ws = (char*)d_ws;
    bf16*  wt_qkv  = (bf16*)(ws + WT_QKV_OFF);
    bf16*  wt_proj = (bf16*)(ws + WT_PROJ_OFF);
    float* cb2     = (float*)(ws + CB_OFF);

    prep_wqkv <<<768, 256, 0, stream>>>(qkv_w, wt_qkv);
    prep_wproj<<<256, 256, 0, stream>>>(proj_w, wt_proj);
    prep_cb2  <<<(64 * 8 * 4096 + 255) / 256, 256, 0, stream>>>(bias_table, rel_index, mask, cb2);

    fused_attn<<<4096, 512, 0, stream>>>(x, qkv_b, proj_b, wt_qkv, wt_proj, cb2, out);
}

// Round 3
// 439.543 us; speedup vs baseline: 1.9410x; 1.9410x over previous
//
#include <hip/hip_runtime.h>
#include <hip/hip_bf16.h>

// ---------------------------------------------------------------------------
// Swin WindowAttention fused kernel, v3: v2 dataflow, spill-free.
//   - __launch_bounds__(512,2): VGPR cap 128 (v2's (512,4) capped at 64 ->
//     2.2 GB scratch spill traffic; that was the whole regression)
//   - QKV split into 3 passes (q,k,v): acc[2][4]=32 VGPR each, x-tile re-read
//     from LDS (cheap) instead of holding 64-96 VGPR of accumulators
//   - attn-out written to LDS inside the qt loop -> oT[2] (8 VGPR) not [2][4]
//   - q,k transposed in-register via identity-MFMA; V/P fragments lane-local
//     by construction (swapped-operand scores, K=16 PV). LDS = 32 KiB only.
// ---------------------------------------------------------------------------

#define NTOK 49
static constexpr float SCALE_Q = 0.17677669529663687f; // 32^-0.5

using bf16   = __bf16;
using bf16x4 = __attribute__((ext_vector_type(4))) __bf16;
using bf16x8 = __attribute__((ext_vector_type(8))) __bf16;
using short4v = __attribute__((ext_vector_type(4))) short;
using f32x4  = __attribute__((ext_vector_type(4))) float;

#define WT_QKV_OFF 0
#define WT_PROJ_OFF (768 * 256 * 2)
#define CB_OFF (WT_PROJ_OFF + 256 * 256 * 2)
#define WS_NEEDED (CB_OFF + (size_t)64 * 8 * 4096 * 4)

// ---- 16x16x16 bf16 MFMA wrapper (builtin-name portability) ----
static __device__ __forceinline__ f32x4 mfma16(bf16x4 a, bf16x4 b, f32x4 c) {
#if __has_builtin(__builtin_amdgcn_mfma_f32_16x16x16_bf16)
    return __builtin_amdgcn_mfma_f32_16x16x16_bf16(a, b, c, 0, 0, 0);
#elif __has_builtin(__builtin_amdgcn_mfma_f32_16x16x16bf16_1k)
    return __builtin_amdgcn_mfma_f32_16x16x16bf16_1k(
        __builtin_bit_cast(short4v, a), __builtin_bit_cast(short4v, b), c, 0, 0, 0);
#elif __has_builtin(__builtin_amdgcn_mfma_f32_16x16x16_bf16_1k)
    return __builtin_amdgcn_mfma_f32_16x16x16_bf16_1k(
        __builtin_bit_cast(short4v, a), __builtin_bit_cast(short4v, b), c, 0, 0, 0);
#else
    asm volatile("v_mfma_f32_16x16x16_bf16 %0, %1, %2, %0\n\t"
                 "s_nop 7\n\ts_nop 7\n\ts_nop 1"
                 : "+v"(c) : "v"(a), "v"(b));
    return c;
#endif
}

// ---- precompute kernels ----
__global__ void prep_wqkv(const float* __restrict__ qkv_w, bf16* __restrict__ wt) {
    int idx = blockIdx.x * 256 + threadIdx.x;            // 768*256
    if (idx >= 768 * 256) return;
    int n = idx >> 8, k = idx & 255;
    float v = qkv_w[k * 768 + n];
    if (n < 256) v *= SCALE_Q;                           // fold q-scale
    wt[idx] = (bf16)v;                                   // wt[n][k]
}
__global__ void prep_wproj(const float* __restrict__ proj_w, bf16* __restrict__ wt) {
    int idx = blockIdx.x * 256 + threadIdx.x;            // 256*256
    if (idx >= 256 * 256) return;
    int n = idx >> 8, k = idx & 255;
    wt[idx] = (bf16)proj_w[k * 256 + n];                 // wt[n][k]
}
// cb2[w][h][kt][qt][r][lane]: score addend for q=16qt+(lane&15),
// key=16kt+4*(lane>>4)+r.  -1e30 for key>=49 (pad), 0 for q>=49 (dead rows).
__global__ void prep_cb2(const float* __restrict__ bias_table, const int* __restrict__ rel_index,
                         const float* __restrict__ mask, float* __restrict__ cb2) {
    int idx = blockIdx.x * 256 + threadIdx.x;            // 64*8*4*4*4*64
    if (idx >= 64 * 8 * 4096) return;
    int lane = idx & 63;
    int t = idx >> 6;
    int r  = t & 3; t >>= 2;
    int qt = t & 3; t >>= 2;
    int kt = t & 3; t >>= 2;
    int h  = t & 7;
    int w  = t >> 3;
    int i = qt * 16 + (lane & 15);
    int j = kt * 16 + (lane >> 4) * 4 + r;
    float v;
    if (j >= NTOK)      v = -1e30f;
    else if (i >= NTOK) v = 0.0f;
    else v = bias_table[rel_index[i * 49 + j] * 8 + h] + mask[(w * 49 + i) * 49 + j];
    cb2[idx] = v;
}

__global__ __launch_bounds__(512, 2) void fused_attn(
    const float* __restrict__ x,
    const float* __restrict__ qkv_b,
    const float* __restrict__ proj_b,
    const bf16* __restrict__ wt_qkv,
    const bf16* __restrict__ wt_proj,
    const float* __restrict__ cb2,
    float* __restrict__ out)
{
    __shared__ char xs[32768];       // x tile (bf16, swizzled); later attn-out
    const int b    = blockIdx.x;
    const int tid  = threadIdx.x;
    const int lane = tid & 63;
    const int h    = tid >> 6;       // wave id == head
    const int c    = lane & 15;
    const int g    = lane >> 4;

    // ---- stage x -> xs (bf16, rows 49..63 zeroed, swizzled) ----
    {
        const float* xb = x + (size_t)b * (NTOK * 256);
        #pragma unroll
        for (int it = 0; it < 8; ++it) {
            int idx = it * 512 + tid;          // 64 rows x 64 float4-chunks
            int row = idx >> 6, c4 = idx & 63;
            float4 v = make_float4(0.f, 0.f, 0.f, 0.f);
            if (row < NTOK) v = ((const float4*)xb)[row * 64 + c4];
            bf16x4 o;
            o[0] = (bf16)v.x; o[1] = (bf16)v.y; o[2] = (bf16)v.z; o[3] = (bf16)v.w;
            *(bf16x4*)(xs + row * 512 + ((c4 * 8) ^ ((row & 7) << 4))) = o;
        }
    }
    __syncthreads();

    // identity B-fragment for the transpose-MFMA: B[k][col] = (k==col)
    bf16x4 iden;
    #pragma unroll
    for (int j = 0; j < 4; ++j) iden[j] = (bf16)((4 * g + j == c) ? 1.0f : 0.0f);

    bf16x4 qf[4][2];   // [qt][ct]  B-frag for scores
    bf16x4 kf[4][2];   // [kt][ct]  A-frag for scores
    bf16x4 vf[2][4];   // [dt][kt]  A-frag for PV

    // ---- QKV pass Q: [64x256] @ [256x32], +bias, transpose -> qf ----
    {
        f32x4 acc[2][4];
        #pragma unroll
        for (int ni = 0; ni < 2; ++ni)
            #pragma unroll
            for (int mi = 0; mi < 4; ++mi)
                acc[ni][mi] = (f32x4){0.f, 0.f, 0.f, 0.f};
        #pragma unroll
        for (int kk = 0; kk < 8; ++kk) {
            bf16x8 a[4];
            #pragma unroll
            for (int mi = 0; mi < 4; ++mi) {
                int row = mi * 16 + c;
                a[mi] = *(const bf16x8*)(xs + row * 512 + ((kk * 64 + g * 16) ^ ((row & 7) << 4)));
            }
            #pragma unroll
            for (int ni = 0; ni < 2; ++ni) {
                int ncol = h * 32 + ni * 16 + c;
                bf16x8 bfr = *(const bf16x8*)(wt_qkv + ncol * 256 + kk * 32 + g * 8);
                #pragma unroll
                for (int mi = 0; mi < 4; ++mi)
                    acc[ni][mi] = __builtin_amdgcn_mfma_f32_16x16x32_bf16(a[mi], bfr, acc[ni][mi], 0, 0, 0);
            }
        }
        #pragma unroll
        for (int ni = 0; ni < 2; ++ni) {
            float bias = qkv_b[h * 32 + ni * 16 + c] * SCALE_Q;
            #pragma unroll
            for (int mi = 0; mi < 4; ++mi) {
                bf16x4 in;
                #pragma unroll
                for (int r = 0; r < 4; ++r) in[r] = (bf16)(acc[ni][mi][r] + bias);
                f32x4 t = mfma16(in, iden, (f32x4){0.f, 0.f, 0.f, 0.f});
                #pragma unroll
                for (int r = 0; r < 4; ++r) qf[mi][ni][r] = (bf16)t[r];
            }
        }
    }

    // ---- QKV pass K: +bias, transpose -> kf ----
    {
        f32x4 acc[2][4];
        #pragma unroll
        for (int ni = 0; ni < 2; ++ni)
            #pragma unroll
            for (int mi = 0; mi < 4; ++mi)
                acc[ni][mi] = (f32x4){0.f, 0.f, 0.f, 0.f};
        #pragma unroll
        for (int kk = 0; kk < 8; ++kk) {
            bf16x8 a[4];
            #pragma unroll
            for (int mi = 0; mi < 4; ++mi) {
                int row = mi * 16 + c;
                a[mi] = *(const bf16x8*)(xs + row * 512 + ((kk * 64 + g * 16) ^ ((row & 7) << 4)));
            }
            #pragma unroll
            for (int ni = 0; ni < 2; ++ni) {
                int ncol = 256 + h * 32 + ni * 16 + c;
                bf16x8 bfr = *(const bf16x8*)(wt_qkv + ncol * 256 + kk * 32 + g * 8);
                #pragma unroll
                for (int mi = 0; mi < 4; ++mi)
                    acc[ni][mi] = __builtin_amdgcn_mfma_f32_16x16x32_bf16(a[mi], bfr, acc[ni][mi], 0, 0, 0);
            }
        }
        #pragma unroll
        for (int ni = 0; ni < 2; ++ni) {
            float bias = qkv_b[256 + h * 32 + ni * 16 + c];
            #pragma unroll
            for (int mi = 0; mi < 4; ++mi) {
                bf16x4 in;
                #pragma unroll
                for (int r = 0; r < 4; ++r) in[r] = (bf16)(acc[ni][mi][r] + bias);
                f32x4 t = mfma16(in, iden, (f32x4){0.f, 0.f, 0.f, 0.f});
                #pragma unroll
                for (int r = 0; r < 4; ++r) kf[mi][ni][r] = (bf16)t[r];
            }
        }
    }

    // ---- QKV pass V: C-frag == PV A-frag, no transform -> vf ----
    {
        f32x4 acc[2][4];
        #pragma unroll
        for (int dt = 0; dt < 2; ++dt)
            #pragma unroll
            for (int mi = 0; mi < 4; ++mi)
                acc[dt][mi] = (f32x4){0.f, 0.f, 0.f, 0.f};
        #pragma unroll
        for (int kk = 0; kk < 8; ++kk) {
            bf16x8 a[4];
            #pragma unroll
            for (int mi = 0; mi < 4; ++mi) {
                int row = mi * 16 + c;
                a[mi] = *(const bf16x8*)(xs + row * 512 + ((kk * 64 + g * 16) ^ ((row & 7) << 4)));
            }
            #pragma unroll
            for (int dt = 0; dt < 2; ++dt) {
                int ncol = 512 + h * 32 + dt * 16 + c;
                bf16x8 bfr = *(const bf16x8*)(wt_qkv + ncol * 256 + kk * 32 + g * 8);
                #pragma unroll
                for (int mi = 0; mi < 4; ++mi)
                    acc[dt][mi] = __builtin_amdgcn_mfma_f32_16x16x32_bf16(a[mi], bfr, acc[dt][mi], 0, 0, 0);
            }
        }
        #pragma unroll
        for (int dt = 0; dt < 2; ++dt) {
            float vb = qkv_b[512 + h * 32 + dt * 16 + c];
            #pragma unroll
            for (int kt = 0; kt < 4; ++kt)
                #pragma unroll
                for (int r = 0; r < 4; ++r) vf[dt][kt][r] = (bf16)(acc[dt][kt][r] + vb);
        }
    }
    __syncthreads();   // last xs read done; xs becomes attn-out buffer

    // ---- attention: per q-tile scores -> softmax -> PV -> xs ----
    const float* cbw = cb2 + ((size_t)((b & 63) * 8 + h)) * 4096;
    #pragma unroll
    for (int qt = 0; qt < 4; ++qt) {
        f32x4 sT[4];
        #pragma unroll
        for (int kt = 0; kt < 4; ++kt) {
            sT[kt] = (f32x4){0.f, 0.f, 0.f, 0.f};
            sT[kt] = mfma16(kf[kt][0], qf[qt][0], sT[kt]);
            sT[kt] = mfma16(kf[kt][1], qf[qt][1], sT[kt]);
        }
        // + (rel_bias + mask + keypad) in exact lane layout, coalesced
        #pragma unroll
        for (int kt = 0; kt < 4; ++kt)
            #pragma unroll
            for (int r = 0; r < 4; ++r)
                sT[kt][r] += cbw[((kt * 4 + qt) * 4 + r) * 64 + lane];
        // softmax over 64 keys: 16 in-lane + reduce across the 4 g-lanes
        float m = sT[0][0];
        #pragma unroll
        for (int kt = 0; kt < 4; ++kt)
            #pragma unroll
            for (int r = 0; r < 4; ++r) m = fmaxf(m, sT[kt][r]);
        m = fmaxf(m, __shfl_xor(m, 16));
        m = fmaxf(m, __shfl_xor(m, 32));
        float sum = 0.f;
        #pragma unroll
        for (int kt = 0; kt < 4; ++kt)
            #pragma unroll
            for (int r = 0; r < 4; ++r) {
                float e = __expf(sT[kt][r] - m);
                sT[kt][r] = e;
                sum += e;
            }
        sum += __shfl_xor(sum, 16);
        sum += __shfl_xor(sum, 32);
        float rs = 1.f / sum;
        bf16x4 pB[4];
        #pragma unroll
        for (int kt = 0; kt < 4; ++kt)
            #pragma unroll
            for (int r = 0; r < 4; ++r) pB[kt][r] = (bf16)(sT[kt][r] * rs);
        // PV for this q-tile only; write straight to xs, free the regs
        #pragma unroll
        for (int dt = 0; dt < 2; ++dt) {
            f32x4 oT = (f32x4){0.f, 0.f, 0.f, 0.f};
            #pragma unroll
            for (int kt = 0; kt < 4; ++kt)
                oT = mfma16(vf[dt][kt], pB[kt], oT);
            int row = qt * 16 + c;
            int cbyte = h * 64 + dt * 32 + g * 8;
            bf16x4 o;
            #pragma unroll
            for (int r = 0; r < 4; ++r) o[r] = (bf16)oT[r];
            *(bf16x4*)(xs + row * 512 + (cbyte ^ ((row & 7) << 4))) = o;
        }
    }
    __syncthreads();

    // ---- proj: [64x256] @ [256x32] per wave + bias -> out ----
    {
        f32x4 po[2][4];
        #pragma unroll
        for (int ni = 0; ni < 2; ++ni)
            #pragma unroll
            for (int mi = 0; mi < 4; ++mi)
                po[ni][mi] = (f32x4){0.f, 0.f, 0.f, 0.f};

        #pragma unroll
        for (int kk = 0; kk < 8; ++kk) {
            bf16x8 a[4];
            #pragma unroll
            for (int mi = 0; mi < 4; ++mi) {
                int row = mi * 16 + c;
                a[mi] = *(const bf16x8*)(xs + row * 512 + ((kk * 64 + g * 16) ^ ((row & 7) << 4)));
            }
            #pragma unroll
            for (int ni = 0; ni < 2; ++ni) {
                int col = h * 32 + ni * 16 + c;
                bf16x8 bw = *(const bf16x8*)(wt_proj + col * 256 + kk * 32 + g * 8);
                #pragma unroll
                for (int mi = 0; mi < 4; ++mi)
                    po[ni][mi] = __builtin_amdgcn_mfma_f32_16x16x32_bf16(a[mi], bw, po[ni][mi], 0, 0, 0);
            }
        }
        float* outb = out + (size_t)b * (NTOK * 256);
        #pragma unroll
        for (int ni = 0; ni < 2; ++ni) {
            int col = h * 32 + ni * 16 + c;
            float pb = proj_b[col];
            #pragma unroll
            for (int mi = 0; mi < 4; ++mi) {
                #pragma unroll
                for (int r = 0; r < 4; ++r) {
                    int row = mi * 16 + g * 4 + r;
                    if (row < NTOK) outb[row * 256 + col] = po[ni][mi][r] + pb;
                }
            }
        }
    }
}

extern "C" void kernel_launch(void* const* d_in, const int* in_sizes, int n_in,
                              void* d_out, int out_size, void* d_ws, size_t ws_size,
                              hipStream_t stream) {
    const float* x          = (const float*)d_in[0];
    const float* mask       = (const float*)d_in[1];
    const float* qkv_w      = (const float*)d_in[2];
    const float* qkv_b      = (const float*)d_in[3];
    const float* proj_w     = (const float*)d_in[4];
    const float* proj_b     = (const float*)d_in[5];
    const float* bias_table = (const float*)d_in[6];
    const int*   rel_index  = (const int*)d_in[7];
    float* out = (float*)d_out;

    if (ws_size < WS_NEEDED) return;  // needs ~8.9 MB scratch

    char* ws = (char*)d_ws;
    bf16*  wt_qkv  = (bf16*)(ws + WT_QKV_OFF);
    bf16*  wt_proj = (bf16*)(ws + WT_PROJ_OFF);
    float* cb2     = (float*)(ws + CB_OFF);

    prep_wqkv <<<768, 256, 0, stream>>>(qkv_w, wt_qkv);
    prep_wproj<<<256, 256, 0, stream>>>(proj_w, wt_proj);
    prep_cb2  <<<(64 * 8 * 4096 + 255) / 256, 256, 0, stream>>>(bias_table, rel_index, mask, cb2);

    fused_attn<<<4096, 512, 0, stream>>>(x, qkv_b, proj_b, wt_qkv, wt_proj, cb2, out);
}

// Round 4
// 424.792 us; speedup vs baseline: 2.0084x; 1.0347x over previous
//
#include <hip/hip_runtime.h>
#include <hip/hip_bf16.h>

// ---------------------------------------------------------------------------
// Swin WindowAttention fused kernel, v4.
//   - ONE merged QKV pass (acc[6][4]): xs A-tile read once, not 3x
//     (LDS-serial floor ~107us -> ~70us/CU), single MFMA chain.
//   - cb2 relaid out as [w][h][kt*4+qt][lane][r]: one f32x4 load per (qt,kt),
//     issued before the score MFMAs (latency cover).
//   - s_setprio(1) around MFMA clusters (T5).
//   - __launch_bounds__(512,2): arg2 = min BLOCKS/CU on this toolchain
//     (R2 evidence: (512,4) capped VGPR at 64 -> spills); cap 128.
//   - q,k transposed in-register via identity-MFMA; V/P fragments lane-local
//     by construction (swapped-operand scores, K=16 PV). LDS = 32 KiB.
// ---------------------------------------------------------------------------

#define NTOK 49
static constexpr float SCALE_Q = 0.17677669529663687f; // 32^-0.5

using bf16   = __bf16;
using bf16x4 = __attribute__((ext_vector_type(4))) __bf16;
using bf16x8 = __attribute__((ext_vector_type(8))) __bf16;
using short4v = __attribute__((ext_vector_type(4))) short;
using f32x4  = __attribute__((ext_vector_type(4))) float;

#define WT_QKV_OFF 0
#define WT_PROJ_OFF (768 * 256 * 2)
#define CB_OFF (WT_PROJ_OFF + 256 * 256 * 2)
#define WS_NEEDED (CB_OFF + (size_t)64 * 8 * 4096 * 4)

// ---- 16x16x16 bf16 MFMA wrapper (builtin-name portability) ----
static __device__ __forceinline__ f32x4 mfma16(bf16x4 a, bf16x4 b, f32x4 c) {
#if __has_builtin(__builtin_amdgcn_mfma_f32_16x16x16_bf16)
    return __builtin_amdgcn_mfma_f32_16x16x16_bf16(a, b, c, 0, 0, 0);
#elif __has_builtin(__builtin_amdgcn_mfma_f32_16x16x16bf16_1k)
    return __builtin_amdgcn_mfma_f32_16x16x16bf16_1k(
        __builtin_bit_cast(short4v, a), __builtin_bit_cast(short4v, b), c, 0, 0, 0);
#elif __has_builtin(__builtin_amdgcn_mfma_f32_16x16x16_bf16_1k)
    return __builtin_amdgcn_mfma_f32_16x16x16_bf16_1k(
        __builtin_bit_cast(short4v, a), __builtin_bit_cast(short4v, b), c, 0, 0, 0);
#else
    asm volatile("v_mfma_f32_16x16x16_bf16 %0, %1, %2, %0\n\t"
                 "s_nop 7\n\ts_nop 7\n\ts_nop 1"
                 : "+v"(c) : "v"(a), "v"(b));
    return c;
#endif
}

// ---- precompute kernels ----
__global__ void prep_wqkv(const float* __restrict__ qkv_w, bf16* __restrict__ wt) {
    int idx = blockIdx.x * 256 + threadIdx.x;            // 768*256
    if (idx >= 768 * 256) return;
    int n = idx >> 8, k = idx & 255;
    float v = qkv_w[k * 768 + n];
    if (n < 256) v *= SCALE_Q;                           // fold q-scale
    wt[idx] = (bf16)v;                                   // wt[n][k]
}
__global__ void prep_wproj(const float* __restrict__ proj_w, bf16* __restrict__ wt) {
    int idx = blockIdx.x * 256 + threadIdx.x;            // 256*256
    if (idx >= 256 * 256) return;
    int n = idx >> 8, k = idx & 255;
    wt[idx] = (bf16)proj_w[k * 256 + n];                 // wt[n][k]
}
// cb2[w][h][kt*4+qt][lane][r]: score addend for q=16qt+(lane&15),
// key=16kt+4*(lane>>4)+r.  -1e30 for key>=49 (pad), 0 for q>=49 (dead rows).
// Lane-major layout -> each lane loads one aligned f32x4 per (qt,kt).
__global__ void prep_cb2(const float* __restrict__ bias_table, const int* __restrict__ rel_index,
                         const float* __restrict__ mask, float* __restrict__ cb2) {
    int idx = blockIdx.x * 256 + threadIdx.x;            // 64*8*16*64*4
    if (idx >= 64 * 8 * 4096) return;
    int r    = idx & 3;
    int lane = (idx >> 2) & 63;
    int qp   = (idx >> 8) & 15;    // kt*4+qt
    int h    = (idx >> 12) & 7;
    int w    = idx >> 15;
    int kt = qp >> 2, qt = qp & 3;
    int i = qt * 16 + (lane & 15);
    int j = kt * 16 + (lane >> 4) * 4 + r;
    float v;
    if (j >= NTOK)      v = -1e30f;
    else if (i >= NTOK) v = 0.0f;
    else v = bias_table[rel_index[i * 49 + j] * 8 + h] + mask[(w * 49 + i) * 49 + j];
    cb2[idx] = v;
}

__global__ __launch_bounds__(512, 2) void fused_attn(
    const float* __restrict__ x,
    const float* __restrict__ qkv_b,
    const float* __restrict__ proj_b,
    const bf16* __restrict__ wt_qkv,
    const bf16* __restrict__ wt_proj,
    const float* __restrict__ cb2,
    float* __restrict__ out)
{
    __shared__ char xs[32768];       // x tile (bf16, swizzled); later attn-out
    const int b    = blockIdx.x;
    const int tid  = threadIdx.x;
    const int lane = tid & 63;
    const int h    = tid >> 6;       // wave id == head
    const int c    = lane & 15;
    const int g    = lane >> 4;

    // ---- stage x -> xs (bf16, rows 49..63 zeroed, swizzled) ----
    {
        const float* xb = x + (size_t)b * (NTOK * 256);
        #pragma unroll
        for (int it = 0; it < 8; ++it) {
            int idx = it * 512 + tid;          // 64 rows x 64 float4-chunks
            int row = idx >> 6, c4 = idx & 63;
            float4 v = make_float4(0.f, 0.f, 0.f, 0.f);
            if (row < NTOK) v = ((const float4*)xb)[row * 64 + c4];
            bf16x4 o;
            o[0] = (bf16)v.x; o[1] = (bf16)v.y; o[2] = (bf16)v.z; o[3] = (bf16)v.w;
            *(bf16x4*)(xs + row * 512 + ((c4 * 8) ^ ((row & 7) << 4))) = o;
        }
    }
    __syncthreads();

    // identity B-fragment for the transpose-MFMA: B[k][col] = (k==col)
    bf16x4 iden;
    #pragma unroll
    for (int j = 0; j < 4; ++j) iden[j] = (bf16)((4 * g + j == c) ? 1.0f : 0.0f);

    bf16x4 qf[4][2];   // [qt][ct]  B-frag for scores
    bf16x4 kf[4][2];   // [kt][ct]  A-frag for scores
    bf16x4 vf[2][4];   // [dt][kt]  A-frag for PV

    // ---- merged QKV: [64x256] @ [256x96] per wave, single pass ----
    {
        f32x4 acc[6][4];
        #pragma unroll
        for (int ni = 0; ni < 6; ++ni)
            #pragma unroll
            for (int mi = 0; mi < 4; ++mi)
                acc[ni][mi] = (f32x4){0.f, 0.f, 0.f, 0.f};

        __builtin_amdgcn_s_setprio(1);
        #pragma unroll
        for (int kk = 0; kk < 8; ++kk) {
            bf16x8 a[4];
            #pragma unroll
            for (int mi = 0; mi < 4; ++mi) {
                int row = mi * 16 + c;
                a[mi] = *(const bf16x8*)(xs + row * 512 + ((kk * 64 + g * 16) ^ ((row & 7) << 4)));
            }
            #pragma unroll
            for (int ni = 0; ni < 6; ++ni) {
                int ncol = (ni >> 1) * 256 + h * 32 + (ni & 1) * 16 + c;
                bf16x8 bfr = *(const bf16x8*)(wt_qkv + ncol * 256 + kk * 32 + g * 8);
                #pragma unroll
                for (int mi = 0; mi < 4; ++mi)
                    acc[ni][mi] = __builtin_amdgcn_mfma_f32_16x16x32_bf16(a[mi], bfr, acc[ni][mi], 0, 0, 0);
            }
        }
        __builtin_amdgcn_s_setprio(0);

        // epilogue: +bias; q,k transposed via identity-MFMA; v packed verbatim
        #pragma unroll
        for (int ni = 0; ni < 6; ++ni) {
            int col = (ni >> 1) * 256 + h * 32 + (ni & 1) * 16 + c;
            float bias = qkv_b[col];
            if (ni < 2) bias *= SCALE_Q;
            #pragma unroll
            for (int mi = 0; mi < 4; ++mi) {
                bf16x4 in;
                #pragma unroll
                for (int r = 0; r < 4; ++r) in[r] = (bf16)(acc[ni][mi][r] + bias);
                if (ni < 4) {
                    f32x4 t = mfma16(in, iden, (f32x4){0.f, 0.f, 0.f, 0.f});
                    bf16x4 o;
                    #pragma unroll
                    for (int r = 0; r < 4; ++r) o[r] = (bf16)t[r];
                    if (ni < 2) qf[mi][ni] = o;
                    else        kf[mi][ni - 2] = o;
                } else {
                    vf[ni - 4][mi] = in;
                }
            }
        }
    }
    __syncthreads();   // all xs reads done; xs becomes attn-out buffer

    // ---- attention: per q-tile scores -> softmax -> PV -> xs ----
    const float* cbw = cb2 + ((size_t)((b & 63) * 8 + h)) * 4096;
    #pragma unroll
    for (int qt = 0; qt < 4; ++qt) {
        // issue cb loads first (vector, coalesced) so score MFMAs cover latency
        f32x4 cbv[4];
        #pragma unroll
        for (int kt = 0; kt < 4; ++kt)
            cbv[kt] = *(const f32x4*)(cbw + (kt * 4 + qt) * 256 + lane * 4);

        f32x4 sT[4];
        __builtin_amdgcn_s_setprio(1);
        #pragma unroll
        for (int kt = 0; kt < 4; ++kt) {
            sT[kt] = (f32x4){0.f, 0.f, 0.f, 0.f};
            sT[kt] = mfma16(kf[kt][0], qf[qt][0], sT[kt]);
            sT[kt] = mfma16(kf[kt][1], qf[qt][1], sT[kt]);
        }
        __builtin_amdgcn_s_setprio(0);
        #pragma unroll
        for (int kt = 0; kt < 4; ++kt)
            #pragma unroll
            for (int r = 0; r < 4; ++r)
                sT[kt][r] += cbv[kt][r];
        // softmax over 64 keys: 16 in-lane + reduce across the 4 g-lanes
        float m = sT[0][0];
        #pragma unroll
        for (int kt = 0; kt < 4; ++kt)
            #pragma unroll
            for (int r = 0; r < 4; ++r) m = fmaxf(m, sT[kt][r]);
        m = fmaxf(m, __shfl_xor(m, 16));
        m = fmaxf(m, __shfl_xor(m, 32));
        float sum = 0.f;
        #pragma unroll
        for (int kt = 0; kt < 4; ++kt)
            #pragma unroll
            for (int r = 0; r < 4; ++r) {
                float e = __expf(sT[kt][r] - m);
                sT[kt][r] = e;
                sum += e;
            }
        sum += __shfl_xor(sum, 16);
        sum += __shfl_xor(sum, 32);
        float rs = 1.f / sum;
        bf16x4 pB[4];
        #pragma unroll
        for (int kt = 0; kt < 4; ++kt)
            #pragma unroll
            for (int r = 0; r < 4; ++r) pB[kt][r] = (bf16)(sT[kt][r] * rs);
        // PV for this q-tile only; write straight to xs, free the regs
        __builtin_amdgcn_s_setprio(1);
        #pragma unroll
        for (int dt = 0; dt < 2; ++dt) {
            f32x4 oT = (f32x4){0.f, 0.f, 0.f, 0.f};
            #pragma unroll
            for (int kt = 0; kt < 4; ++kt)
                oT = mfma16(vf[dt][kt], pB[kt], oT);
            int row = qt * 16 + c;
            int cbyte = h * 64 + dt * 32 + g * 8;
            bf16x4 o;
            #pragma unroll
            for (int r = 0; r < 4; ++r) o[r] = (bf16)oT[r];
            *(bf16x4*)(xs + row * 512 + (cbyte ^ ((row & 7) << 4))) = o;
        }
        __builtin_amdgcn_s_setprio(0);
    }
    __syncthreads();

    // ---- proj: [64x256] @ [256x32] per wave + bias -> out ----
    {
        f32x4 po[2][4];
        #pragma unroll
        for (int ni = 0; ni < 2; ++ni)
            #pragma unroll
            for (int mi = 0; mi < 4; ++mi)
                po[ni][mi] = (f32x4){0.f, 0.f, 0.f, 0.f};

        __builtin_amdgcn_s_setprio(1);
        #pragma unroll
        for (int kk = 0; kk < 8; ++kk) {
            bf16x8 a[4];
            #pragma unroll
            for (int mi = 0; mi < 4; ++mi) {
                int row = mi * 16 + c;
                a[mi] = *(const bf16x8*)(xs + row * 512 + ((kk * 64 + g * 16) ^ ((row & 7) << 4)));
            }
            #pragma unroll
            for (int ni = 0; ni < 2; ++ni) {
                int col = h * 32 + ni * 16 + c;
                bf16x8 bw = *(const bf16x8*)(wt_proj + col * 256 + kk * 32 + g * 8);
                #pragma unroll
                for (int mi = 0; mi < 4; ++mi)
                    po[ni][mi] = __builtin_amdgcn_mfma_f32_16x16x32_bf16(a[mi], bw, po[ni][mi], 0, 0, 0);
            }
        }
        __builtin_amdgcn_s_setprio(0);
        float* outb = out + (size_t)b * (NTOK * 256);
        #pragma unroll
        for (int ni = 0; ni < 2; ++ni) {
            int col = h * 32 + ni * 16 + c;
            float pb = proj_b[col];
            #pragma unroll
            for (int mi = 0; mi < 4; ++mi) {
                #pragma unroll
                for (int r = 0; r < 4; ++r) {
                    int row = mi * 16 + g * 4 + r;
                    if (row < NTOK) outb[row * 256 + col] = po[ni][mi][r] + pb;
                }
            }
        }
    }
}

extern "C" void kernel_launch(void* const* d_in, const int* in_sizes, int n_in,
                              void* d_out, int out_size, void* d_ws, size_t ws_size,
                              hipStream_t stream) {
    const float* x          = (const float*)d_in[0];
    const float* mask       = (const float*)d_in[1];
    const float* qkv_w      = (const float*)d_in[2];
    const float* qkv_b      = (const float*)d_in[3];
    const float* proj_w     = (const float*)d_in[4];
    const float* proj_b     = (const float*)d_in[5];
    const float* bias_table = (const float*)d_in[6];
    const int*   rel_index  = (const int*)d_in[7];
    float* out = (float*)d_out;

    if (ws_size < WS_NEEDED) return;  // needs ~8.9 MB scratch

    char* ws = (char*)d_ws;
    bf16*  wt_qkv  = (bf16*)(ws + WT_QKV_OFF);
    bf16*  wt_proj = (bf16*)(ws + WT_PROJ_OFF);
    float* cb2     = (float*)(ws + CB_OFF);

    prep_wqkv <<<768, 256, 0, stream>>>(qkv_w, wt_qkv);
    prep_wproj<<<256, 256, 0, stream>>>(proj_w, wt_proj);
    prep_cb2  <<<(64 * 8 * 4096 + 255) / 256, 256, 0, stream>>>(bias_table, rel_index, mask, cb2);

    fused_attn<<<4096, 512, 0, stream>>>(x, qkv_b, proj_b, wt_qkv, wt_proj, cb2, out);
}

// Round 5
// 424.532 us; speedup vs baseline: 2.0096x; 1.0006x over previous
//
#include <hip/hip_runtime.h>
#include <hip/hip_bf16.h>

// ---------------------------------------------------------------------------
// Swin WindowAttention fused kernel, v5.
//   - bias+mask table split: sb[h][...] (128 KB, w-independent, L2-hot for
//     every block) + sm[w][...] (16 KB/window, h-independent, staged in LDS
//     during x staging). Kills the 8 MB cb2 table's L3 latency on the attn
//     critical path and its 512 MB/dispatch cache stream.
//   - LDS 48 KB (32K x-tile + 16K window mask) -> still 2 blocks/CU.
//   - ONE merged QKV pass; q,k transposed in-register via identity-MFMA;
//     V/P fragments lane-local (swapped-operand scores, K=16 PV).
//   - __launch_bounds__(512,2): arg2 = min BLOCKS/CU on this toolchain
//     (R2 evidence: (512,4) capped VGPR at 64 -> spill disaster); cap 128.
// ---------------------------------------------------------------------------

#define NTOK 49
static constexpr float SCALE_Q = 0.17677669529663687f; // 32^-0.5

using bf16   = __bf16;
using bf16x4 = __attribute__((ext_vector_type(4))) __bf16;
using bf16x8 = __attribute__((ext_vector_type(8))) __bf16;
using short4v = __attribute__((ext_vector_type(4))) short;
using f32x4  = __attribute__((ext_vector_type(4))) float;

#define WT_QKV_OFF 0
#define WT_PROJ_OFF (768 * 256 * 2)
#define SB_OFF (WT_PROJ_OFF + 256 * 256 * 2)
#define SM_OFF (SB_OFF + 8 * 4096 * 4)
#define WS_NEEDED (SM_OFF + (size_t)64 * 4096 * 4)

// ---- 16x16x16 bf16 MFMA wrapper (builtin-name portability) ----
static __device__ __forceinline__ f32x4 mfma16(bf16x4 a, bf16x4 b, f32x4 c) {
#if __has_builtin(__builtin_amdgcn_mfma_f32_16x16x16_bf16)
    return __builtin_amdgcn_mfma_f32_16x16x16_bf16(a, b, c, 0, 0, 0);
#elif __has_builtin(__builtin_amdgcn_mfma_f32_16x16x16bf16_1k)
    return __builtin_amdgcn_mfma_f32_16x16x16bf16_1k(
        __builtin_bit_cast(short4v, a), __builtin_bit_cast(short4v, b), c, 0, 0, 0);
#elif __has_builtin(__builtin_amdgcn_mfma_f32_16x16x16_bf16_1k)
    return __builtin_amdgcn_mfma_f32_16x16x16_bf16_1k(
        __builtin_bit_cast(short4v, a), __builtin_bit_cast(short4v, b), c, 0, 0, 0);
#else
    asm volatile("v_mfma_f32_16x16x16_bf16 %0, %1, %2, %0\n\t"
                 "s_nop 7\n\ts_nop 7\n\ts_nop 1"
                 : "+v"(c) : "v"(a), "v"(b));
    return c;
#endif
}

// ---- precompute kernels ----
__global__ void prep_wqkv(const float* __restrict__ qkv_w, bf16* __restrict__ wt) {
    int idx = blockIdx.x * 256 + threadIdx.x;            // 768*256
    if (idx >= 768 * 256) return;
    int n = idx >> 8, k = idx & 255;
    float v = qkv_w[k * 768 + n];
    if (n < 256) v *= SCALE_Q;                           // fold q-scale
    wt[idx] = (bf16)v;                                   // wt[n][k]
}
__global__ void prep_wproj(const float* __restrict__ proj_w, bf16* __restrict__ wt) {
    int idx = blockIdx.x * 256 + threadIdx.x;            // 256*256
    if (idx >= 256 * 256) return;
    int n = idx >> 8, k = idx & 255;
    wt[idx] = (bf16)proj_w[k * 256 + n];                 // wt[n][k]
}
// sb[h][qp][lane][r]: rel-bias part for q=16qt+(lane&15), key=16kt+4*(lane>>4)+r
// (qp = kt*4+qt). -1e30 for key>=49 (pad); 0 for q>=49 (dead rows).
__global__ void prep_sb(const float* __restrict__ bias_table, const int* __restrict__ rel_index,
                        float* __restrict__ sb) {
    int idx = blockIdx.x * 256 + threadIdx.x;            // 8*4096
    if (idx >= 8 * 4096) return;
    int r    = idx & 3;
    int lane = (idx >> 2) & 63;
    int qp   = (idx >> 8) & 15;
    int h    = idx >> 12;
    int kt = qp >> 2, qt = qp & 3;
    int i = qt * 16 + (lane & 15);
    int j = kt * 16 + (lane >> 4) * 4 + r;
    float v;
    if (j >= NTOK)      v = -1e30f;
    else if (i >= NTOK) v = 0.0f;
    else v = bias_table[rel_index[i * 49 + j] * 8 + h];
    sb[idx] = v;
}
// sm[w][qp][lane][r]: window-mask part (0 on padded rows/cols).
__global__ void prep_sm(const float* __restrict__ mask, float* __restrict__ sm) {
    int idx = blockIdx.x * 256 + threadIdx.x;            // 64*4096
    if (idx >= 64 * 4096) return;
    int r    = idx & 3;
    int lane = (idx >> 2) & 63;
    int qp   = (idx >> 8) & 15;
    int w    = idx >> 12;
    int kt = qp >> 2, qt = qp & 3;
    int i = qt * 16 + (lane & 15);
    int j = kt * 16 + (lane >> 4) * 4 + r;
    sm[idx] = (i < NTOK && j < NTOK) ? mask[(w * 49 + i) * 49 + j] : 0.0f;
}

__global__ __launch_bounds__(512, 2) void fused_attn(
    const float* __restrict__ x,
    const float* __restrict__ qkv_b,
    const float* __restrict__ proj_b,
    const bf16* __restrict__ wt_qkv,
    const bf16* __restrict__ wt_proj,
    const float* __restrict__ sb,
    const float* __restrict__ sm,
    float* __restrict__ out)
{
    __shared__ char smem[49152];     // 32K x-tile (later attn-out) + 16K mask
    char* xs  = smem;
    char* smL = smem + 32768;
    const int b    = blockIdx.x;
    const int tid  = threadIdx.x;
    const int lane = tid & 63;
    const int h    = tid >> 6;       // wave id == head
    const int c    = lane & 15;
    const int g    = lane >> 4;

    // ---- stage x -> xs (bf16, rows 49..63 zeroed, swizzled) + sm -> smL ----
    {
        const float* xb = x + (size_t)b * (NTOK * 256);
        #pragma unroll
        for (int it = 0; it < 8; ++it) {
            int idx = it * 512 + tid;          // 64 rows x 64 float4-chunks
            int row = idx >> 6, c4 = idx & 63;
            float4 v = make_float4(0.f, 0.f, 0.f, 0.f);
            if (row < NTOK) v = ((const float4*)xb)[row * 64 + c4];
            bf16x4 o;
            o[0] = (bf16)v.x; o[1] = (bf16)v.y; o[2] = (bf16)v.z; o[3] = (bf16)v.w;
            *(bf16x4*)(xs + row * 512 + ((c4 * 8) ^ ((row & 7) << 4))) = o;
        }
        const float4* smw = (const float4*)(sm + (size_t)(b & 63) * 4096);
        #pragma unroll
        for (int t = 0; t < 2; ++t) {
            int off = t * 512 + tid;           // 1024 float4 = 16 KB
            *(float4*)(smL + off * 16) = smw[off];
        }
    }
    __syncthreads();

    // identity B-fragment for the transpose-MFMA: B[k][col] = (k==col)
    bf16x4 iden;
    #pragma unroll
    for (int j = 0; j < 4; ++j) iden[j] = (bf16)((4 * g + j == c) ? 1.0f : 0.0f);

    bf16x4 qf[4][2];   // [qt][ct]  B-frag for scores
    bf16x4 kf[4][2];   // [kt][ct]  A-frag for scores
    bf16x4 vf[2][4];   // [dt][kt]  A-frag for PV

    // ---- merged QKV: [64x256] @ [256x96] per wave, single pass ----
    {
        f32x4 acc[6][4];
        #pragma unroll
        for (int ni = 0; ni < 6; ++ni)
            #pragma unroll
            for (int mi = 0; mi < 4; ++mi)
                acc[ni][mi] = (f32x4){0.f, 0.f, 0.f, 0.f};

        __builtin_amdgcn_s_setprio(1);
        #pragma unroll
        for (int kk = 0; kk < 8; ++kk) {
            bf16x8 a[4];
            #pragma unroll
            for (int mi = 0; mi < 4; ++mi) {
                int row = mi * 16 + c;
                a[mi] = *(const bf16x8*)(xs + row * 512 + ((kk * 64 + g * 16) ^ ((row & 7) << 4)));
            }
            #pragma unroll
            for (int ni = 0; ni < 6; ++ni) {
                int ncol = (ni >> 1) * 256 + h * 32 + (ni & 1) * 16 + c;
                bf16x8 bfr = *(const bf16x8*)(wt_qkv + ncol * 256 + kk * 32 + g * 8);
                #pragma unroll
                for (int mi = 0; mi < 4; ++mi)
                    acc[ni][mi] = __builtin_amdgcn_mfma_f32_16x16x32_bf16(a[mi], bfr, acc[ni][mi], 0, 0, 0);
            }
        }
        __builtin_amdgcn_s_setprio(0);

        // epilogue: +bias; q,k transposed via identity-MFMA; v packed verbatim
        #pragma unroll
        for (int ni = 0; ni < 6; ++ni) {
            int col = (ni >> 1) * 256 + h * 32 + (ni & 1) * 16 + c;
            float bias = qkv_b[col];
            if (ni < 2) bias *= SCALE_Q;
            #pragma unroll
            for (int mi = 0; mi < 4; ++mi) {
                bf16x4 in;
                #pragma unroll
                for (int r = 0; r < 4; ++r) in[r] = (bf16)(acc[ni][mi][r] + bias);
                if (ni < 4) {
                    f32x4 t = mfma16(in, iden, (f32x4){0.f, 0.f, 0.f, 0.f});
                    bf16x4 o;
                    #pragma unroll
                    for (int r = 0; r < 4; ++r) o[r] = (bf16)t[r];
                    if (ni < 2) qf[mi][ni] = o;
                    else        kf[mi][ni - 2] = o;
                } else {
                    vf[ni - 4][mi] = in;
                }
            }
        }
    }
    __syncthreads();   // all xs reads done; xs becomes attn-out buffer

    // ---- attention: per q-tile scores -> softmax -> PV -> xs ----
    const float* sbh = sb + (size_t)h * 4096;
    #pragma unroll
    for (int qt = 0; qt < 4; ++qt) {
        // bias part from L2-hot 128 KB table; mask part from LDS
        f32x4 sbv[4], smv[4];
        #pragma unroll
        for (int kt = 0; kt < 4; ++kt)
            sbv[kt] = *(const f32x4*)(sbh + (kt * 4 + qt) * 256 + lane * 4);
        #pragma unroll
        for (int kt = 0; kt < 4; ++kt)
            smv[kt] = *(const f32x4*)(smL + ((kt * 4 + qt) * 64 + lane) * 16);

        f32x4 sT[4];
        __builtin_amdgcn_s_setprio(1);
        #pragma unroll
        for (int kt = 0; kt < 4; ++kt) {
            sT[kt] = (f32x4){0.f, 0.f, 0.f, 0.f};
            sT[kt] = mfma16(kf[kt][0], qf[qt][0], sT[kt]);
            sT[kt] = mfma16(kf[kt][1], qf[qt][1], sT[kt]);
        }
        __builtin_amdgcn_s_setprio(0);
        #pragma unroll
        for (int kt = 0; kt < 4; ++kt)
            #pragma unroll
            for (int r = 0; r < 4; ++r)
                sT[kt][r] += sbv[kt][r] + smv[kt][r];
        // softmax over 64 keys: 16 in-lane + reduce across the 4 g-lanes
        float m = sT[0][0];
        #pragma unroll
        for (int kt = 0; kt < 4; ++kt)
            #pragma unroll
            for (int r = 0; r < 4; ++r) m = fmaxf(m, sT[kt][r]);
        m = fmaxf(m, __shfl_xor(m, 16));
        m = fmaxf(m, __shfl_xor(m, 32));
        float sum = 0.f;
        #pragma unroll
        for (int kt = 0; kt < 4; ++kt)
            #pragma unroll
            for (int r = 0; r < 4; ++r) {
                float e = __expf(sT[kt][r] - m);
                sT[kt][r] = e;
                sum += e;
            }
        sum += __shfl_xor(sum, 16);
        sum += __shfl_xor(sum, 32);
        float rs = 1.f / sum;
        bf16x4 pB[4];
        #pragma unroll
        for (int kt = 0; kt < 4; ++kt)
            #pragma unroll
            for (int r = 0; r < 4; ++r) pB[kt][r] = (bf16)(sT[kt][r] * rs);
        // PV for this q-tile only; write straight to xs, free the regs
        __builtin_amdgcn_s_setprio(1);
        #pragma unroll
        for (int dt = 0; dt < 2; ++dt) {
            f32x4 oT = (f32x4){0.f, 0.f, 0.f, 0.f};
            #pragma unroll
            for (int kt = 0; kt < 4; ++kt)
                oT = mfma16(vf[dt][kt], pB[kt], oT);
            int row = qt * 16 + c;
            int cbyte = h * 64 + dt * 32 + g * 8;
            bf16x4 o;
            #pragma unroll
            for (int r = 0; r < 4; ++r) o[r] = (bf16)oT[r];
            *(bf16x4*)(xs + row * 512 + (cbyte ^ ((row & 7) << 4))) = o;
        }
        __builtin_amdgcn_s_setprio(0);
    }
    __syncthreads();

    // ---- proj: [64x256] @ [256x32] per wave + bias -> out ----
    {
        f32x4 po[2][4];
        #pragma unroll
        for (int ni = 0; ni < 2; ++ni)
            #pragma unroll
            for (int mi = 0; mi < 4; ++mi)
                po[ni][mi] = (f32x4){0.f, 0.f, 0.f, 0.f};

        __builtin_amdgcn_s_setprio(1);
        #pragma unroll
        for (int kk = 0; kk < 8; ++kk) {
            bf16x8 a[4];
            #pragma unroll
            for (int mi = 0; mi < 4; ++mi) {
                int row = mi * 16 + c;
                a[mi] = *(const bf16x8*)(xs + row * 512 + ((kk * 64 + g * 16) ^ ((row & 7) << 4)));
            }
            #pragma unroll
            for (int ni = 0; ni < 2; ++ni) {
                int col = h * 32 + ni * 16 + c;
                bf16x8 bw = *(const bf16x8*)(wt_proj + col * 256 + kk * 32 + g * 8);
                #pragma unroll
                for (int mi = 0; mi < 4; ++mi)
                    po[ni][mi] = __builtin_amdgcn_mfma_f32_16x16x32_bf16(a[mi], bw, po[ni][mi], 0, 0, 0);
            }
        }
        __builtin_amdgcn_s_setprio(0);
        float* outb = out + (size_t)b * (NTOK * 256);
        #pragma unroll
        for (int ni = 0; ni < 2; ++ni) {
            int col = h * 32 + ni * 16 + c;
            float pb = proj_b[col];
            #pragma unroll
            for (int mi = 0; mi < 4; ++mi) {
                #pragma unroll
                for (int r = 0; r < 4; ++r) {
                    int row = mi * 16 + g * 4 + r;
                    if (row < NTOK) outb[row * 256 + col] = po[ni][mi][r] + pb;
                }
            }
        }
    }
}

extern "C" void kernel_launch(void* const* d_in, const int* in_sizes, int n_in,
                              void* d_out, int out_size, void* d_ws, size_t ws_size,
                              hipStream_t stream) {
    const float* x          = (const float*)d_in[0];
    const float* mask       = (const float*)d_in[1];
    const float* qkv_w      = (const float*)d_in[2];
    const float* qkv_b      = (const float*)d_in[3];
    const float* proj_w     = (const float*)d_in[4];
    const float* proj_b     = (const float*)d_in[5];
    const float* bias_table = (const float*)d_in[6];
    const int*   rel_index  = (const int*)d_in[7];
    float* out = (float*)d_out;

    if (ws_size < WS_NEEDED) return;  // needs ~1.7 MB scratch

    char* ws = (char*)d_ws;
    bf16*  wt_qkv  = (bf16*)(ws + WT_QKV_OFF);
    bf16*  wt_proj = (bf16*)(ws + WT_PROJ_OFF);
    float* sbp     = (float*)(ws + SB_OFF);
    float* smp     = (float*)(ws + SM_OFF);

    prep_wqkv <<<768, 256, 0, stream>>>(qkv_w, wt_qkv);
    prep_wproj<<<256, 256, 0, stream>>>(proj_w, wt_proj);
    prep_sb   <<<128, 256, 0, stream>>>(bias_table, rel_index, sbp);
    prep_sm   <<<1024, 256, 0, stream>>>(mask, smp);

    fused_attn<<<4096, 512, 0, stream>>>(x, qkv_b, proj_b, wt_qkv, wt_proj, sbp, smp, out);
}

// Round 6
// 394.296 us; speedup vs baseline: 2.1637x; 1.0767x over previous
//
#include <hip/hip_runtime.h>
#include <hip/hip_bf16.h>

// ---------------------------------------------------------------------------
// Swin WindowAttention fused kernel, v6: memory-level parallelism.
//   - QKV split QK/V passes so per-kk weight loads batch 4-wide (resp 2-wide)
//     in registers BEFORE use (one latency exposure per kk, not per load).
//     R3 lesson: compiler does NOT batch loads on its own; source order and
//     register headroom (acc 64 not 96) are both required.
//   - stage: 8 x-loads into regs first, then cvt+LDS-write (1 exposure not 8)
//   - proj: 2-wide weight-load batch per kk.
//   - sm read straight from its 1MB L2-resident table (LDS staging gave 0).
//   - setprio only around attn MFMAs (m190/m191 evidence).
//   - q,k transposed in-register via identity-MFMA; V/P fragments lane-local
//     (swapped-operand scores, K=16 PV). LDS = 32 KiB. launch_bounds(512,2).
// ---------------------------------------------------------------------------

#define NTOK 49
static constexpr float SCALE_Q = 0.17677669529663687f; // 32^-0.5

using bf16   = __bf16;
using bf16x4 = __attribute__((ext_vector_type(4))) __bf16;
using bf16x8 = __attribute__((ext_vector_type(8))) __bf16;
using short4v = __attribute__((ext_vector_type(4))) short;
using f32x4  = __attribute__((ext_vector_type(4))) float;

#define WT_QKV_OFF 0
#define WT_PROJ_OFF (768 * 256 * 2)
#define SB_OFF (WT_PROJ_OFF + 256 * 256 * 2)
#define SM_OFF (SB_OFF + 8 * 4096 * 4)
#define WS_NEEDED (SM_OFF + (size_t)64 * 4096 * 4)

// ---- 16x16x16 bf16 MFMA wrapper (builtin-name portability) ----
static __device__ __forceinline__ f32x4 mfma16(bf16x4 a, bf16x4 b, f32x4 c) {
#if __has_builtin(__builtin_amdgcn_mfma_f32_16x16x16_bf16)
    return __builtin_amdgcn_mfma_f32_16x16x16_bf16(a, b, c, 0, 0, 0);
#elif __has_builtin(__builtin_amdgcn_mfma_f32_16x16x16bf16_1k)
    return __builtin_amdgcn_mfma_f32_16x16x16bf16_1k(
        __builtin_bit_cast(short4v, a), __builtin_bit_cast(short4v, b), c, 0, 0, 0);
#elif __has_builtin(__builtin_amdgcn_mfma_f32_16x16x16_bf16_1k)
    return __builtin_amdgcn_mfma_f32_16x16x16_bf16_1k(
        __builtin_bit_cast(short4v, a), __builtin_bit_cast(short4v, b), c, 0, 0, 0);
#else
    asm volatile("v_mfma_f32_16x16x16_bf16 %0, %1, %2, %0\n\t"
                 "s_nop 7\n\ts_nop 7\n\ts_nop 1"
                 : "+v"(c) : "v"(a), "v"(b));
    return c;
#endif
}

// ---- precompute kernels ----
__global__ void prep_wqkv(const float* __restrict__ qkv_w, bf16* __restrict__ wt) {
    int idx = blockIdx.x * 256 + threadIdx.x;            // 768*256
    if (idx >= 768 * 256) return;
    int n = idx >> 8, k = idx & 255;
    float v = qkv_w[k * 768 + n];
    if (n < 256) v *= SCALE_Q;                           // fold q-scale
    wt[idx] = (bf16)v;                                   // wt[n][k]
}
__global__ void prep_wproj(const float* __restrict__ proj_w, bf16* __restrict__ wt) {
    int idx = blockIdx.x * 256 + threadIdx.x;            // 256*256
    if (idx >= 256 * 256) return;
    int n = idx >> 8, k = idx & 255;
    wt[idx] = (bf16)proj_w[k * 256 + n];                 // wt[n][k]
}
// sb[h][qp][lane][r]: rel-bias part for q=16qt+(lane&15), key=16kt+4*(lane>>4)+r
// (qp = kt*4+qt). -1e30 for key>=49 (pad); 0 for q>=49 (dead rows).
__global__ void prep_sb(const float* __restrict__ bias_table, const int* __restrict__ rel_index,
                        float* __restrict__ sb) {
    int idx = blockIdx.x * 256 + threadIdx.x;            // 8*4096
    if (idx >= 8 * 4096) return;
    int r    = idx & 3;
    int lane = (idx >> 2) & 63;
    int qp   = (idx >> 8) & 15;
    int h    = idx >> 12;
    int kt = qp >> 2, qt = qp & 3;
    int i = qt * 16 + (lane & 15);
    int j = kt * 16 + (lane >> 4) * 4 + r;
    float v;
    if (j >= NTOK)      v = -1e30f;
    else if (i >= NTOK) v = 0.0f;
    else v = bias_table[rel_index[i * 49 + j] * 8 + h];
    sb[idx] = v;
}
// sm[w][qp][lane][r]: window-mask part (0 on padded rows/cols).
__global__ void prep_sm(const float* __restrict__ mask, float* __restrict__ sm) {
    int idx = blockIdx.x * 256 + threadIdx.x;            // 64*4096
    if (idx >= 64 * 4096) return;
    int r    = idx & 3;
    int lane = (idx >> 2) & 63;
    int qp   = (idx >> 8) & 15;
    int w    = idx >> 12;
    int kt = qp >> 2, qt = qp & 3;
    int i = qt * 16 + (lane & 15);
    int j = kt * 16 + (lane >> 4) * 4 + r;
    sm[idx] = (i < NTOK && j < NTOK) ? mask[(w * 49 + i) * 49 + j] : 0.0f;
}

__global__ __launch_bounds__(512, 2) void fused_attn(
    const float* __restrict__ x,
    const float* __restrict__ qkv_b,
    const float* __restrict__ proj_b,
    const bf16* __restrict__ wt_qkv,
    const bf16* __restrict__ wt_proj,
    const float* __restrict__ sb,
    const float* __restrict__ sm,
    float* __restrict__ out)
{
    __shared__ char xs[32768];       // x tile (bf16, swizzled); later attn-out
    const int b    = blockIdx.x;
    const int tid  = threadIdx.x;
    const int lane = tid & 63;
    const int h    = tid >> 6;       // wave id == head
    const int c    = lane & 15;
    const int g    = lane >> 4;

    // ---- stage x -> xs: load ALL 8 float4 first (batched), then cvt+write --
    {
        const float* xb = x + (size_t)b * (NTOK * 256);
        float4 xr[8];
        #pragma unroll
        for (int it = 0; it < 8; ++it) {
            int idx = it * 512 + tid;          // 64 rows x 64 float4-chunks
            int row = idx >> 6, c4 = idx & 63;
            xr[it] = make_float4(0.f, 0.f, 0.f, 0.f);
            if (row < NTOK) xr[it] = ((const float4*)xb)[row * 64 + c4];
        }
        #pragma unroll
        for (int it = 0; it < 8; ++it) {
            int idx = it * 512 + tid;
            int row = idx >> 6, c4 = idx & 63;
            bf16x4 o;
            o[0] = (bf16)xr[it].x; o[1] = (bf16)xr[it].y;
            o[2] = (bf16)xr[it].z; o[3] = (bf16)xr[it].w;
            *(bf16x4*)(xs + row * 512 + ((c4 * 8) ^ ((row & 7) << 4))) = o;
        }
    }
    __syncthreads();

    // identity B-fragment for the transpose-MFMA: B[k][col] = (k==col)
    bf16x4 iden;
    #pragma unroll
    for (int j = 0; j < 4; ++j) iden[j] = (bf16)((4 * g + j == c) ? 1.0f : 0.0f);

    bf16x4 qf[4][2];   // [qt][ct]  B-frag for scores
    bf16x4 kf[4][2];   // [kt][ct]  A-frag for scores
    bf16x4 vf[2][4];   // [dt][kt]  A-frag for PV

    // ---- pass QK: [64x256] @ [256x64], weight loads batched 4-wide per kk --
    {
        f32x4 acc[4][4];
        #pragma unroll
        for (int ni = 0; ni < 4; ++ni)
            #pragma unroll
            for (int mi = 0; mi < 4; ++mi)
                acc[ni][mi] = (f32x4){0.f, 0.f, 0.f, 0.f};

        #pragma unroll
        for (int kk = 0; kk < 8; ++kk) {
            // 4 independent global loads issued before ANY use
            bf16x8 bb[4];
            #pragma unroll
            for (int ni = 0; ni < 4; ++ni) {
                int ncol = (ni >> 1) * 256 + h * 32 + (ni & 1) * 16 + c;
                bb[ni] = *(const bf16x8*)(wt_qkv + ncol * 256 + kk * 32 + g * 8);
            }
            bf16x8 a[4];
            #pragma unroll
            for (int mi = 0; mi < 4; ++mi) {
                int row = mi * 16 + c;
                a[mi] = *(const bf16x8*)(xs + row * 512 + ((kk * 64 + g * 16) ^ ((row & 7) << 4)));
            }
            #pragma unroll
            for (int ni = 0; ni < 4; ++ni)
                #pragma unroll
                for (int mi = 0; mi < 4; ++mi)
                    acc[ni][mi] = __builtin_amdgcn_mfma_f32_16x16x32_bf16(a[mi], bb[ni], acc[ni][mi], 0, 0, 0);
        }
        // epilogue: +bias, pack bf16, in-register transpose via identity-MFMA
        #pragma unroll
        for (int ni = 0; ni < 4; ++ni) {
            int col = (ni >> 1) * 256 + h * 32 + (ni & 1) * 16 + c;
            float bias = qkv_b[col];
            if (ni < 2) bias *= SCALE_Q;
            #pragma unroll
            for (int mi = 0; mi < 4; ++mi) {
                bf16x4 in;
                #pragma unroll
                for (int r = 0; r < 4; ++r) in[r] = (bf16)(acc[ni][mi][r] + bias);
                f32x4 t = mfma16(in, iden, (f32x4){0.f, 0.f, 0.f, 0.f});
                bf16x4 o;
                #pragma unroll
                for (int r = 0; r < 4; ++r) o[r] = (bf16)t[r];
                if (ni < 2) qf[mi][ni] = o;
                else        kf[mi][ni - 2] = o;
            }
        }
    }

    // ---- pass V: [64x256] @ [256x32], loads batched 2-wide per kk ----
    {
        f32x4 acc[2][4];
        #pragma unroll
        for (int dt = 0; dt < 2; ++dt)
            #pragma unroll
            for (int mi = 0; mi < 4; ++mi)
                acc[dt][mi] = (f32x4){0.f, 0.f, 0.f, 0.f};

        #pragma unroll
        for (int kk = 0; kk < 8; ++kk) {
            bf16x8 bv[2];
            #pragma unroll
            for (int dt = 0; dt < 2; ++dt) {
                int ncol = 512 + h * 32 + dt * 16 + c;
                bv[dt] = *(const bf16x8*)(wt_qkv + ncol * 256 + kk * 32 + g * 8);
            }
            bf16x8 a[4];
            #pragma unroll
            for (int mi = 0; mi < 4; ++mi) {
                int row = mi * 16 + c;
                a[mi] = *(const bf16x8*)(xs + row * 512 + ((kk * 64 + g * 16) ^ ((row & 7) << 4)));
            }
            #pragma unroll
            for (int dt = 0; dt < 2; ++dt)
                #pragma unroll
                for (int mi = 0; mi < 4; ++mi)
                    acc[dt][mi] = __builtin_amdgcn_mfma_f32_16x16x32_bf16(a[mi], bv[dt], acc[dt][mi], 0, 0, 0);
        }
        #pragma unroll
        for (int dt = 0; dt < 2; ++dt) {
            float vb = qkv_b[512 + h * 32 + dt * 16 + c];
            #pragma unroll
            for (int kt = 0; kt < 4; ++kt)
                #pragma unroll
                for (int r = 0; r < 4; ++r) vf[dt][kt][r] = (bf16)(acc[dt][kt][r] + vb);
        }
    }
    __syncthreads();   // all xs reads done; xs becomes attn-out buffer

    // ---- attention: per q-tile scores -> softmax -> PV -> xs ----
    const float* sbh = sb + (size_t)h * 4096;
    const float* smw = sm + (size_t)(b & 63) * 4096;
    #pragma unroll
    for (int qt = 0; qt < 4; ++qt) {
        // 8 independent table loads in flight before the score MFMAs
        f32x4 sbv[4], smv[4];
        #pragma unroll
        for (int kt = 0; kt < 4; ++kt)
            sbv[kt] = *(const f32x4*)(sbh + (kt * 4 + qt) * 256 + lane * 4);
        #pragma unroll
        for (int kt = 0; kt < 4; ++kt)
            smv[kt] = *(const f32x4*)(smw + (kt * 4 + qt) * 256 + lane * 4);

        f32x4 sT[4];
        __builtin_amdgcn_s_setprio(1);
        #pragma unroll
        for (int kt = 0; kt < 4; ++kt) {
            sT[kt] = (f32x4){0.f, 0.f, 0.f, 0.f};
            sT[kt] = mfma16(kf[kt][0], qf[qt][0], sT[kt]);
            sT[kt] = mfma16(kf[kt][1], qf[qt][1], sT[kt]);
        }
        __builtin_amdgcn_s_setprio(0);
        #pragma unroll
        for (int kt = 0; kt < 4; ++kt)
            #pragma unroll
            for (int r = 0; r < 4; ++r)
                sT[kt][r] += sbv[kt][r] + smv[kt][r];
        // softmax over 64 keys: 16 in-lane + reduce across the 4 g-lanes
        float m = sT[0][0];
        #pragma unroll
        for (int kt = 0; kt < 4; ++kt)
            #pragma unroll
            for (int r = 0; r < 4; ++r) m = fmaxf(m, sT[kt][r]);
        m = fmaxf(m, __shfl_xor(m, 16));
        m = fmaxf(m, __shfl_xor(m, 32));
        float sum = 0.f;
        #pragma unroll
        for (int kt = 0; kt < 4; ++kt)
            #pragma unroll
            for (int r = 0; r < 4; ++r) {
                float e = __expf(sT[kt][r] - m);
                sT[kt][r] = e;
                sum += e;
            }
        sum += __shfl_xor(sum, 16);
        sum += __shfl_xor(sum, 32);
        float rs = 1.f / sum;
        bf16x4 pB[4];
        #pragma unroll
        for (int kt = 0; kt < 4; ++kt)
            #pragma unroll
            for (int r = 0; r < 4; ++r) pB[kt][r] = (bf16)(sT[kt][r] * rs);
        // PV for this q-tile only; write straight to xs, free the regs
        __builtin_amdgcn_s_setprio(1);
        #pragma unroll
        for (int dt = 0; dt < 2; ++dt) {
            f32x4 oT = (f32x4){0.f, 0.f, 0.f, 0.f};
            #pragma unroll
            for (int kt = 0; kt < 4; ++kt)
                oT = mfma16(vf[dt][kt], pB[kt], oT);
            int row = qt * 16 + c;
            int cbyte = h * 64 + dt * 32 + g * 8;
            bf16x4 o;
            #pragma unroll
            for (int r = 0; r < 4; ++r) o[r] = (bf16)oT[r];
            *(bf16x4*)(xs + row * 512 + (cbyte ^ ((row & 7) << 4))) = o;
        }
        __builtin_amdgcn_s_setprio(0);
    }
    __syncthreads();

    // ---- proj: [64x256] @ [256x32] per wave, loads batched 2-wide ----
    {
        f32x4 po[2][4];
        #pragma unroll
        for (int ni = 0; ni < 2; ++ni)
            #pragma unroll
            for (int mi = 0; mi < 4; ++mi)
                po[ni][mi] = (f32x4){0.f, 0.f, 0.f, 0.f};

        #pragma unroll
        for (int kk = 0; kk < 8; ++kk) {
            bf16x8 bw[2];
            #pragma unroll
            for (int ni = 0; ni < 2; ++ni) {
                int col = h * 32 + ni * 16 + c;
                bw[ni] = *(const bf16x8*)(wt_proj + col * 256 + kk * 32 + g * 8);
            }
            bf16x8 a[4];
            #pragma unroll
            for (int mi = 0; mi < 4; ++mi) {
                int row = mi * 16 + c;
                a[mi] = *(const bf16x8*)(xs + row * 512 + ((kk * 64 + g * 16) ^ ((row & 7) << 4)));
            }
            #pragma unroll
            for (int ni = 0; ni < 2; ++ni)
                #pragma unroll
                for (int mi = 0; mi < 4; ++mi)
                    po[ni][mi] = __builtin_amdgcn_mfma_f32_16x16x32_bf16(a[mi], bw[ni], po[ni][mi], 0, 0, 0);
        }
        float* outb = out + (size_t)b * (NTOK * 256);
        #pragma unroll
        for (int ni = 0; ni < 2; ++ni) {
            int col = h * 32 + ni * 16 + c;
            float pb = proj_b[col];
            #pragma unroll
            for (int mi = 0; mi < 4; ++mi) {
                #pragma unroll
                for (int r = 0; r < 4; ++r) {
                    int row = mi * 16 + g * 4 + r;
                    if (row < NTOK) outb[row * 256 + col] = po[ni][mi][r] + pb;
                }
            }
        }
    }
}

extern "C" void kernel_launch(void* const* d_in, const int* in_sizes, int n_in,
                              void* d_out, int out_size, void* d_ws, size_t ws_size,
                              hipStream_t stream) {
    const float* x          = (const float*)d_in[0];
    const float* mask       = (const float*)d_in[1];
    const float* qkv_w      = (const float*)d_in[2];
    const float* qkv_b      = (const float*)d_in[3];
    const float* proj_w     = (const float*)d_in[4];
    const float* proj_b     = (const float*)d_in[5];
    const float* bias_table = (const float*)d_in[6];
    const int*   rel_index  = (const int*)d_in[7];
    float* out = (float*)d_out;

    if (ws_size < WS_NEEDED) return;  // needs ~1.7 MB scratch

    char* ws = (char*)d_ws;
    bf16*  wt_qkv  = (bf16*)(ws + WT_QKV_OFF);
    bf16*  wt_proj = (bf16*)(ws + WT_PROJ_OFF);
    float* sbp     = (float*)(ws + SB_OFF);
    float* smp     = (float*)(ws + SM_OFF);

    prep_wqkv <<<768, 256, 0, stream>>>(qkv_w, wt_qkv);
    prep_wproj<<<256, 256, 0, stream>>>(proj_w, wt_proj);
    prep_sb   <<<128, 256, 0, stream>>>(bias_table, rel_index, sbp);
    prep_sm   <<<1024, 256, 0, stream>>>(mask, smp);

    fused_attn<<<4096, 512, 0, stream>>>(x, qkv_b, proj_b, wt_qkv, wt_proj, sbp, smp, out);
}